// Round 11
// baseline (86.528 us; speedup 1.0000x reference)
//
#include <hip/hip_runtime.h>
#include <stdint.h>

#define N_PTS 4096
#define BATCH 4
#define C_IN  128
#define C_OUT 256
#define KDIM  1024   // 8 active slots * 128 channels (octant-7 slot provably always zero)
#define NCELL 512    // 8x8x8 spatial grid, cell 0.125 >= radius 0.12
#define BIGJ  0x3fffffff

typedef __attribute__((ext_vector_type(8))) __bf16 bf16x8;
typedef __attribute__((ext_vector_type(4))) float  f32x4;

__device__ inline void gload_lds16(const void* g, void* l) {
    __builtin_amdgcn_global_load_lds(
        (__attribute__((address_space(1))) void*)(void*)(uintptr_t)g,
        (__attribute__((address_space(3))) void*)l, 16, 0, 0);
}

__device__ inline unsigned short f2bf(float v) {
    uint32_t u = __builtin_bit_cast(uint32_t, v);
    return (unsigned short)((u + 0x7fffu + ((u >> 16) & 1u)) >> 16);   // RTNE
}

// reference-exact sq = ((x*x + y*y) + z*z), no FMA contraction
__device__ inline float sq_exact(float x, float y, float z) {
    return __fadd_rn(__fadd_rn(__fmul_rn(x, x), __fmul_rn(y, y)), __fmul_rn(z, z));
}

__device__ inline int cell_of(float x, float y, float z) {
    int cx = (int)(x * 8.0f); cx = min(max(cx, 0), 7);
    int cy = (int)(y * 8.0f); cy = min(max(cy, 0), 7);
    int cz = (int)(z * 8.0f); cz = min(max(cz, 0), 7);
    return (cx << 6) | (cy << 3) | cz;
}

__device__ inline int wmin(int v) {
    for (int off = 32; off >= 1; off >>= 1) v = min(v, __shfl_xor(v, off, 64));
    return v;
}

// ---------------- kernel 1: fused prep (unchanged from round 8/9) ----------------
__global__ __launch_bounds__(256) void fused_prep(const float* __restrict__ w,
                                                  unsigned short* __restrict__ wt,
                                                  const float* __restrict__ x,
                                                  unsigned short* __restrict__ xbf,
                                                  const float* __restrict__ pcs,
                                                  float4* __restrict__ sp4,
                                                  int* __restrict__ cellstart) {
    const int bid = blockIdx.x;
    const int tid = threadIdx.x;

    if (bid < 1024) {
        // ---- weight transpose ----
        int gidx = bid * 256 + tid;                   // 0..262143
        int o = gidx >> 10, k = gidx & 1023;
        int slot = k >> 7, cch = k & 127;             // slot 0=center, slot s=octant s-1
        wt[gidx] = f2bf(w[(size_t)o * 1152 + cch * 9 + slot]);
    } else if (bid < 1284) {
        // ---- feature transpose ----
        __shared__ __attribute__((aligned(16))) unsigned short tile[64 * 132];
        const int bb = bid - 1024;
        const int b = bb / 65;
        const int j0 = (bb % 65) * 64;
        if (j0 < N_PTS) {
            for (int c0 = 0; c0 < C_IN; c0 += 4) {
                int cc = c0 + (tid >> 6);
                int jj = tid & 63;
                float v = x[((size_t)b * C_IN + cc) * N_PTS + j0 + jj];
                tile[jj * 132 + cc] = f2bf(v);
            }
            __syncthreads();
            for (int i = 0; i < 8; ++i) {
                int idx = i * 256 + tid;      // 0..2047 -> 64 rows x 32 quads
                int row = idx >> 5, cq = idx & 31;
                uint2 v = *(const uint2*)&tile[row * 132 + cq * 4];
                *(uint2*)&xbf[((size_t)b * (N_PTS + 1) + j0 + row) * C_IN + cq * 4] = v;
            }
        } else {
            // zeros row j = 4096 (empty-octant gather target)
            for (int i = tid; i < C_IN; i += 256)
                xbf[((size_t)b * (N_PTS + 1) + N_PTS) * C_IN + i] = 0;
        }
    } else {
        // ---- grid build for batch b: count -> prefix -> scatter (LDS) ----
        __shared__ int scnt[NCELL];                   // counts -> cursors
        __shared__ int pairs[256];
        const int b = bid - 1284;
        const float* pb = pcs + (size_t)b * 3 * N_PTS;
        for (int i = tid; i < NCELL; i += 256) scnt[i] = 0;
        __syncthreads();
        // count (16 points per thread)
        for (int k = 0; k < 16; ++k) {
            int n = k * 256 + tid;
            atomicAdd(&scnt[cell_of(pb[n], pb[N_PTS + n], pb[2 * N_PTS + n])], 1);
        }
        __syncthreads();
        // exclusive prefix over 512 cells (2 cells/thread + Hillis-Steele on pair sums)
        const int a0 = scnt[2 * tid], a1 = scnt[2 * tid + 1];
        pairs[tid] = a0 + a1;
        __syncthreads();
        for (int off = 1; off < 256; off <<= 1) {
            int v = (tid >= off) ? pairs[tid - off] : 0;
            __syncthreads();
            pairs[tid] += v;
            __syncthreads();
        }
        const int epair = pairs[tid] - (a0 + a1);     // exclusive pair prefix
        cellstart[b * 513 + 2 * tid]     = epair;
        cellstart[b * 513 + 2 * tid + 1] = epair + a0;
        scnt[2 * tid]     = epair;                    // cursors
        scnt[2 * tid + 1] = epair + a0;
        if (tid == 255) cellstart[b * 513 + 512] = epair + a0 + a1;
        __syncthreads();
        // scatter: sp4[slot] = (x, y, z, bitcast(original index n))
        for (int k = 0; k < 16; ++k) {
            int n = k * 256 + tid;
            float px = pb[n], py = pb[N_PTS + n], pz = pb[2 * N_PTS + n];
            int slot = atomicAdd(&scnt[cell_of(px, py, pz)], 1);
            sp4[(b << 12) + slot] = make_float4(px, py, pz, __builtin_bit_cast(float, n));
        }
    }
}

// ---------------- kernel 2: grid ball query (unchanged from round 9) ----------------
__global__ __launch_bounds__(256) void bq_grid(const float4* __restrict__ sp4,
                                               const int* __restrict__ cellstart,
                                               unsigned short* __restrict__ idxu) {
    __shared__ int lists[4 * 128];
    const int tid = threadIdx.x;
    const int wid = tid >> 6, lane = tid & 63;
    // XCD-chunked bijective swizzle (4096 blocks, 8 XCDs)
    const int lb = ((blockIdx.x & 7) << 9) | (blockIdx.x >> 3);
    const int gw = (lb << 2) | wid;                   // global wave id 0..16383
    const int b = gw >> 12;
    const int sidx = gw & 4095;                       // cell-sorted slot
    const float4* sp = sp4 + ((size_t)b << 12);
    const int* cs = cellstart + b * 513;
    const float4 cp = sp[sidx];
    const float cxf = cp.x, cyf = cp.y, czf = cp.z;
    const int n = __builtin_bit_cast(int, cp.w);      // original center index
    const float csq = sq_exact(cxf, cyf, czf);        // bit-identical to reference
    const float r2 = (float)(0.12 * 0.12);

    int cx = min(max((int)(cxf * 8.0f), 0), 7);
    int cy = min(max((int)(cyf * 8.0f), 0), 7);
    int cz = min(max((int)(czf * 8.0f), 0), 7);
    const int zlo = max(cz - 1, 0), zhi = min(cz + 1, 7);

    // 9-run table (wave-uniform scalars, static names only — rule #20)
#define RUN(k, dx, dy)                                                              \
    int rs##k = 0, ln##k = 0;                                                       \
    {                                                                               \
        int gx = cx + (dx), gy = cy + (dy);                                         \
        if (gx >= 0 && gx <= 7 && gy >= 0 && gy <= 7) {                             \
            int cb_ = (gx << 6) | (gy << 3);                                        \
            rs##k = cs[cb_ + zlo];                                                  \
            ln##k = cs[cb_ + zhi + 1] - rs##k;                                      \
        }                                                                           \
    }
    RUN(0, -1, -1) RUN(1, -1, 0) RUN(2, -1, 1)
    RUN(3,  0, -1) RUN(4,  0, 0) RUN(5,  0, 1)
    RUN(6,  1, -1) RUN(7,  1, 0) RUN(8,  1, 1)
#undef RUN
    const int c1 = ln0;
    const int c2 = c1 + ln1;
    const int c3 = c2 + ln2;
    const int c4 = c3 + ln3;
    const int c5 = c4 + ln4;
    const int c6 = c5 + ln5;
    const int c7 = c6 + ln6;
    const int c8 = c7 + ln7;
    const int TT = c8 + ln8;                          // total candidates (~216 avg)

    // stream position -> cell-sorted slot (static cndmask chain, clamped safe)
#define CAND_IDX(T, OUTI)                                                           \
    {                                                                               \
        const int t_ = (T);                                                         \
        int i_ = rs0 + t_;                                                          \
        i_ = (t_ >= c1) ? (rs1 + t_ - c1) : i_;                                     \
        i_ = (t_ >= c2) ? (rs2 + t_ - c2) : i_;                                     \
        i_ = (t_ >= c3) ? (rs3 + t_ - c3) : i_;                                     \
        i_ = (t_ >= c4) ? (rs4 + t_ - c4) : i_;                                     \
        i_ = (t_ >= c5) ? (rs5 + t_ - c5) : i_;                                     \
        i_ = (t_ >= c6) ? (rs6 + t_ - c6) : i_;                                     \
        i_ = (t_ >= c7) ? (rs7 + t_ - c7) : i_;                                     \
        i_ = (t_ >= c8) ? (rs8 + t_ - c8) : i_;                                     \
        OUTI = (t_ < TT) ? i_ : rs4;   /* rs4 = center's own cell, always valid */  \
    }

    int f0 = BIGJ, f1 = BIGJ, f2 = BIGJ, f3 = BIGJ, f4 = BIGJ, f5 = BIGJ, f6 = BIGJ;
    int cnt = 0;
    int* lst = &lists[wid * 128];
    const unsigned long long ltm = (1ull << lane) - 1ull;

    int ic0;
    CAND_IDX(lane, ic0)
    float4 p_cur = sp[ic0];                           // prologue load (TT >= 1 always)

    for (int t0 = 0; t0 < TT; t0 += 64) {
        int icn;
        CAND_IDX(t0 + 64 + lane, icn)
        const float4 p_nxt = sp[icn];                 // prefetch next chunk

        const bool valid = (t0 + lane) < TT;
        const float4 p = p_cur;
        const int j = __builtin_bit_cast(int, p.w);
        const float psq = sq_exact(p.x, p.y, p.z);    // bit-identical to reference
        float dot = __fadd_rn(__fadd_rn(__fmul_rn(cxf, p.x), __fmul_rn(cyf, p.y)),
                              __fmul_rn(czf, p.z));
        float dd = __fsub_rn(__fadd_rn(csq, psq), __fmul_rn(2.0f, dot));
        const bool ok = valid && (dd <= r2) && (j != n);
        unsigned long long m = __ballot(ok);
        if (m) {
            int pos = cnt + __popcll(m & ltm);
            if (ok && pos < 128) lst[pos] = j;
            cnt += __popcll(m);
            const int oct = ((p.x >= cxf) ? 4 : 0) + ((p.y >= cyf) ? 2 : 0)
                          + ((p.z >= czf) ? 1 : 0);
            const int key = ok ? j : BIGJ;
            f0 = (oct == 0) ? min(f0, key) : f0;
            f1 = (oct == 1) ? min(f1, key) : f1;
            f2 = (oct == 2) ? min(f2, key) : f2;
            f3 = (oct == 3) ? min(f3, key) : f3;
            f4 = (oct == 4) ? min(f4, key) : f4;
            f5 = (oct == 5) ? min(f5, key) : f5;
            f6 = (oct == 6) ? min(f6, key) : f6;
        }
        p_cur = p_nxt;
    }
#undef CAND_IDX

    f0 = wmin(f0); f1 = wmin(f1); f2 = wmin(f2); f3 = wmin(f3);
    f4 = wmin(f4); f5 = wmin(f5); f6 = wmin(f6);

    if (cnt > 31) {
        // rank check against the (<=128) recorded matches; cnt>128 has ~0
        // probability at lambda~30 (same exposure as the sort it replaced)
        const int c2_ = min(cnt, 128);
        const int l0 = (lane < c2_) ? lst[lane] : BIGJ;
        const int l1 = (64 + lane < c2_) ? lst[64 + lane] : BIGJ;
#define RANKCHK(F)                                                                  \
        {                                                                           \
            int r_ = __popcll(__ballot(l0 < F)) + __popcll(__ballot(l1 < F));       \
            F = (r_ <= 30) ? F : BIGJ;                                              \
        }
        RANKCHK(f0) RANKCHK(f1) RANKCHK(f2) RANKCHK(f3)
        RANKCHK(f4) RANKCHK(f5) RANKCHK(f6)
#undef RANKCHK
    }

    int v = n;                                        // lane 0: center index
    if (lane == 1) v = f0;
    if (lane == 2) v = f1;
    if (lane == 3) v = f2;
    if (lane == 4) v = f3;
    if (lane == 5) v = f4;
    if (lane == 6) v = f5;
    if (lane == 7) v = f6;
    if (v > N_PTS) v = N_PTS;                         // BIGJ -> zeros row
    if (lane < 8) idxu[((size_t)((b << 12) | n)) * 8 + lane] = (unsigned short)v;
}

// ---------------- kernel 3: gathered GEMM (unchanged from round 9) ----------------
// NOTE: launched 3x this round as a timing probe — idempotent (reads xbf/wt/idxu/
// bias, writes the same deterministic out values), so correctness holds.
__global__ __launch_bounds__(512) void pconv_gemm(const unsigned short* __restrict__ xbf,
                                                  const unsigned short* __restrict__ wt,
                                                  const unsigned short* __restrict__ idxu,
                                                  const float* __restrict__ bias,
                                                  float* __restrict__ out) {
    __shared__ __attribute__((aligned(16))) unsigned short Plds[2][128 * 64];
    __shared__ __attribute__((aligned(16))) unsigned short Wlds[2][128 * 64];
    __shared__ unsigned short jlds[128 * 8];
    const int tid = threadIdx.x;
    const int tm = blockIdx.x >> 1, tn = blockIdx.x & 1;  // 128 M-tiles x 2 N-tiles
    const int g0 = tm * 128;                 // global point-row base
    const int b  = g0 >> 12;
    const int nb = g0 & 4095;
    const int o0 = tn * 128;
    const int wid = tid >> 6, lane = tid & 63;
    const int wo = wid >> 1, wn = wid & 1;   // wave -> 32 o-rows x 64 n-cols

    // hoist all gather indices for this block (1024 u16, coalesced)
    for (int i = tid; i < 1024; i += 512) jlds[i] = idxu[(size_t)g0 * 8 + i];
    __syncthreads();

    f32x4 acc[2][4] = {};

#define STAGE(BUF, IT)                                                              \
    {                                                                               \
        const int k0_ = (IT) << 6;                                                  \
        const int slot_ = (IT) >> 1;                                                \
        const int cb_ = ((IT) & 1) << 6;                                            \
        _Pragma("unroll")                                                           \
        for (int i_ = 0; i_ < 2; ++i_) {                                            \
            const int Lb_ = i_ * 512 + wid * 64;                                    \
            const int row_ = (Lb_ + lane) >> 3;                                     \
            const int slog_ = (lane & 7) ^ (row_ & 7);                              \
            int j_ = jlds[row_ * 8 + slot_];                                        \
            gload_lds16(xbf + ((size_t)b * (N_PTS + 1) + j_) * C_IN + cb_ + slog_ * 8, \
                        &Plds[BUF][Lb_ * 8]);                                       \
            gload_lds16(wt + (size_t)(o0 + row_) * KDIM + k0_ + slog_ * 8,          \
                        &Wlds[BUF][Lb_ * 8]);                                       \
        }                                                                           \
    }

    STAGE(0, 0)
    __syncthreads();                          // vmcnt(0) drain: buf0 ready

    for (int it = 0; it < 16; ++it) {
        const int cur = it & 1;
        if (it + 1 < 16) STAGE(cur ^ 1, it + 1)   // prefetch next K-step
#pragma unroll
        for (int ks = 0; ks < 2; ++ks) {
            bf16x8 wf[2], pf[4];
#pragma unroll
            for (int f = 0; f < 2; ++f) {
                int orow = wo * 32 + f * 16 + (lane & 15);
                int slw = (ks * 4 + (lane >> 4)) ^ (orow & 7);
                wf[f] = *(const bf16x8*)&Wlds[cur][orow * 64 + slw * 8];
            }
#pragma unroll
            for (int q = 0; q < 4; ++q) {
                int nrow = wn * 64 + q * 16 + (lane & 15);
                int slp = (ks * 4 + (lane >> 4)) ^ (nrow & 7);
                pf[q] = *(const bf16x8*)&Plds[cur][nrow * 64 + slp * 8];
            }
#pragma unroll
            for (int f = 0; f < 2; ++f)
#pragma unroll
                for (int q = 0; q < 4; ++q)
                    acc[f][q] = __builtin_amdgcn_mfma_f32_16x16x32_bf16(
                        wf[f], pf[q], acc[f][q], 0, 0, 0);
        }
        __syncthreads();                      // next buf staged + this buf's reads done
    }
#undef STAGE

#pragma unroll
    for (int f = 0; f < 2; ++f) {
        int o = o0 + wo * 32 + f * 16 + (lane >> 4) * 4;
#pragma unroll
        for (int q = 0; q < 4; ++q) {
            int n = nb + wn * 64 + q * 16 + (lane & 15);
#pragma unroll
            for (int r = 0; r < 4; ++r) {
                out[((size_t)b * C_OUT + o + r) * N_PTS + n] = acc[f][q][r] + bias[o + r];
            }
        }
    }
}

extern "C" void kernel_launch(void* const* d_in, const int* in_sizes, int n_in,
                              void* d_out, int out_size, void* d_ws, size_t ws_size,
                              hipStream_t stream) {
    const float* x    = (const float*)d_in[0];
    const float* pcs  = (const float*)d_in[1];
    const float* w    = (const float*)d_in[2];
    const float* bias = (const float*)d_in[3];

    // ws layout (bytes) — total 5,252,112 (proven-safe range):
    char* base = (char*)d_ws;
    float4* sp4 = (float4*)base;                                    //       0 (262,144)
    unsigned short* xbf = (unsigned short*)(base + 262144);         // 4,195,328
    unsigned short* wt  = (unsigned short*)(base + 4457472);        //   524,288
    unsigned short* idxu = (unsigned short*)(base + 4981760);       //   262,144
    int* cellstart = (int*)(base + 5243904);                        //     8,208
    float* out = (float*)d_out;

    hipLaunchKernelGGL(fused_prep, dim3(1288), dim3(256), 0, stream,
                       w, wt, x, xbf, pcs, sp4, cellstart);
    hipLaunchKernelGGL(bq_grid,    dim3(4096), dim3(256), 0, stream,
                       sp4, cellstart, idxu);
    // TIMING PROBE (this round only): pconv_gemm launched 3x, idempotent.
    // dur_us(R11) - dur_us(R9) = 2*(gemm + ~1.8us gap) -> direct measurement.
    hipLaunchKernelGGL(pconv_gemm, dim3(256),  dim3(512), 0, stream,
                       xbf, wt, idxu, bias, out);
    hipLaunchKernelGGL(pconv_gemm, dim3(256),  dim3(512), 0, stream,
                       xbf, wt, idxu, bias, out);
    hipLaunchKernelGGL(pconv_gemm, dim3(256),  dim3(512), 0, stream,
                       xbf, wt, idxu, bias, out);
}

// Round 12
// 45.065 us; speedup vs baseline: 1.9201x; 1.9201x over previous
//
#include <hip/hip_runtime.h>
#include <stdint.h>

#define N_PTS 4096
#define BATCH 4
#define C_IN  128
#define C_OUT 256
#define KDIM  1024   // 8 active slots * 128 channels (octant-7 slot provably always zero)
#define NCELL 512    // 8x8x8 spatial grid, cell 0.125 >= radius 0.12
#define BIGJ  0x3fffffff

typedef __attribute__((ext_vector_type(8))) __bf16 bf16x8;
typedef __attribute__((ext_vector_type(4))) float  f32x4;

__device__ inline void gload_lds16(const void* g, void* l) {
    __builtin_amdgcn_global_load_lds(
        (__attribute__((address_space(1))) void*)(void*)(uintptr_t)g,
        (__attribute__((address_space(3))) void*)l, 16, 0, 0);
}

__device__ inline unsigned short f2bf(float v) {
    uint32_t u = __builtin_bit_cast(uint32_t, v);
    return (unsigned short)((u + 0x7fffu + ((u >> 16) & 1u)) >> 16);   // RTNE
}

// reference-exact sq = ((x*x + y*y) + z*z), no FMA contraction
__device__ inline float sq_exact(float x, float y, float z) {
    return __fadd_rn(__fadd_rn(__fmul_rn(x, x), __fmul_rn(y, y)), __fmul_rn(z, z));
}

__device__ inline int cell_of(float x, float y, float z) {
    int cx = (int)(x * 8.0f); cx = min(max(cx, 0), 7);
    int cy = (int)(y * 8.0f); cy = min(max(cy, 0), 7);
    int cz = (int)(z * 8.0f); cz = min(max(cz, 0), 7);
    return (cx << 6) | (cy << 3) | cz;
}

__device__ inline int wmin(int v) {
    for (int off = 32; off >= 1; off >>= 1) v = min(v, __shfl_xor(v, off, 64));
    return v;
}

// ---------------- kernel 1: fused prep ----------------
// bid [0,4):        per-batch grid build (FIRST -> starts at t=0, overlaps the rest)
// bid [4,1028):     wt transpose [256,128,1,9] fp32 -> wt[o][kappa] bf16
// bid [1028,1288):  x transpose [B,C,N] fp32 -> xbf [B][N+1][C] bf16 (+zeros row)
__global__ __launch_bounds__(256) void fused_prep(const float* __restrict__ w,
                                                  unsigned short* __restrict__ wt,
                                                  const float* __restrict__ x,
                                                  unsigned short* __restrict__ xbf,
                                                  const float* __restrict__ pcs,
                                                  float4* __restrict__ sp4,
                                                  int* __restrict__ cellstart) {
    const int bid = blockIdx.x;
    const int tid = threadIdx.x;

    if (bid < 4) {
        // ---- grid build for batch b: count -> prefix -> scatter (LDS) ----
        __shared__ int scnt[NCELL];                   // counts -> cursors
        __shared__ int pairs[256];
        const int b = bid;
        const float* pb = pcs + (size_t)b * 3 * N_PTS;
        for (int i = tid; i < NCELL; i += 256) scnt[i] = 0;
        // register-batch all 16 points' coords (one vmcnt wait, not 16 serial)
        float px[16], py[16], pz[16];
#pragma unroll
        for (int k = 0; k < 16; ++k) {
            int n = k * 256 + tid;
            px[k] = pb[n]; py[k] = pb[N_PTS + n]; pz[k] = pb[2 * N_PTS + n];
        }
        __syncthreads();
#pragma unroll
        for (int k = 0; k < 16; ++k)
            atomicAdd(&scnt[cell_of(px[k], py[k], pz[k])], 1);
        __syncthreads();
        // exclusive prefix over 512 cells (2 cells/thread + Hillis-Steele on pair sums)
        const int a0 = scnt[2 * tid], a1 = scnt[2 * tid + 1];
        pairs[tid] = a0 + a1;
        __syncthreads();
        for (int off = 1; off < 256; off <<= 1) {
            int v = (tid >= off) ? pairs[tid - off] : 0;
            __syncthreads();
            pairs[tid] += v;
            __syncthreads();
        }
        const int epair = pairs[tid] - (a0 + a1);     // exclusive pair prefix
        cellstart[b * 513 + 2 * tid]     = epair;
        cellstart[b * 513 + 2 * tid + 1] = epair + a0;
        scnt[2 * tid]     = epair;                    // cursors
        scnt[2 * tid + 1] = epair + a0;
        if (tid == 255) cellstart[b * 513 + 512] = epair + a0 + a1;
        __syncthreads();
        // scatter: sp4[slot] = (x, y, z, bitcast(original index n))
#pragma unroll
        for (int k = 0; k < 16; ++k) {
            int n = k * 256 + tid;
            int slot = atomicAdd(&scnt[cell_of(px[k], py[k], pz[k])], 1);
            sp4[(b << 12) + slot] =
                make_float4(px[k], py[k], pz[k], __builtin_bit_cast(float, n));
        }
    } else if (bid < 1028) {
        // ---- weight transpose ----
        int gidx = (bid - 4) * 256 + tid;             // 0..262143
        int o = gidx >> 10, k = gidx & 1023;
        int slot = k >> 7, cch = k & 127;             // slot 0=center, slot s=octant s-1
        wt[gidx] = f2bf(w[(size_t)o * 1152 + cch * 9 + slot]);
    } else {
        // ---- feature transpose ----
        __shared__ __attribute__((aligned(16))) unsigned short tile[64 * 132];
        const int bb = bid - 1028;
        const int b = bb / 65;
        const int j0 = (bb % 65) * 64;
        if (j0 < N_PTS) {
#pragma unroll
            for (int c0 = 0; c0 < C_IN; c0 += 4) {
                int cc = c0 + (tid >> 6);
                int jj = tid & 63;
                float v = x[((size_t)b * C_IN + cc) * N_PTS + j0 + jj];
                tile[jj * 132 + cc] = f2bf(v);
            }
            __syncthreads();
#pragma unroll
            for (int i = 0; i < 8; ++i) {
                int idx = i * 256 + tid;      // 0..2047 -> 64 rows x 32 quads
                int row = idx >> 5, cq = idx & 31;
                uint2 v = *(const uint2*)&tile[row * 132 + cq * 4];
                *(uint2*)&xbf[((size_t)b * (N_PTS + 1) + j0 + row) * C_IN + cq * 4] = v;
            }
        } else {
            // zeros row j = 4096 (empty-octant gather target)
            for (int i = tid; i < C_IN; i += 256)
                xbf[((size_t)b * (N_PTS + 1) + N_PTS) * C_IN + i] = 0;
        }
    }
}

// ---------------- kernel 2: grid ball query (unchanged from round 9) ----------------
__global__ __launch_bounds__(256) void bq_grid(const float4* __restrict__ sp4,
                                               const int* __restrict__ cellstart,
                                               unsigned short* __restrict__ idxu) {
    __shared__ int lists[4 * 128];
    const int tid = threadIdx.x;
    const int wid = tid >> 6, lane = tid & 63;
    // XCD-chunked bijective swizzle (4096 blocks, 8 XCDs)
    const int lb = ((blockIdx.x & 7) << 9) | (blockIdx.x >> 3);
    const int gw = (lb << 2) | wid;                   // global wave id 0..16383
    const int b = gw >> 12;
    const int sidx = gw & 4095;                       // cell-sorted slot
    const float4* sp = sp4 + ((size_t)b << 12);
    const int* cs = cellstart + b * 513;
    const float4 cp = sp[sidx];
    const float cxf = cp.x, cyf = cp.y, czf = cp.z;
    const int n = __builtin_bit_cast(int, cp.w);      // original center index
    const float csq = sq_exact(cxf, cyf, czf);        // bit-identical to reference
    const float r2 = (float)(0.12 * 0.12);

    int cx = min(max((int)(cxf * 8.0f), 0), 7);
    int cy = min(max((int)(cyf * 8.0f), 0), 7);
    int cz = min(max((int)(czf * 8.0f), 0), 7);
    const int zlo = max(cz - 1, 0), zhi = min(cz + 1, 7);

    // 9-run table (wave-uniform scalars, static names only — rule #20)
#define RUN(k, dx, dy)                                                              \
    int rs##k = 0, ln##k = 0;                                                       \
    {                                                                               \
        int gx = cx + (dx), gy = cy + (dy);                                         \
        if (gx >= 0 && gx <= 7 && gy >= 0 && gy <= 7) {                             \
            int cb_ = (gx << 6) | (gy << 3);                                        \
            rs##k = cs[cb_ + zlo];                                                  \
            ln##k = cs[cb_ + zhi + 1] - rs##k;                                      \
        }                                                                           \
    }
    RUN(0, -1, -1) RUN(1, -1, 0) RUN(2, -1, 1)
    RUN(3,  0, -1) RUN(4,  0, 0) RUN(5,  0, 1)
    RUN(6,  1, -1) RUN(7,  1, 0) RUN(8,  1, 1)
#undef RUN
    const int c1 = ln0;
    const int c2 = c1 + ln1;
    const int c3 = c2 + ln2;
    const int c4 = c3 + ln3;
    const int c5 = c4 + ln4;
    const int c6 = c5 + ln5;
    const int c7 = c6 + ln6;
    const int c8 = c7 + ln7;
    const int TT = c8 + ln8;                          // total candidates (~216 avg)

    // stream position -> cell-sorted slot (static cndmask chain, clamped safe)
#define CAND_IDX(T, OUTI)                                                           \
    {                                                                               \
        const int t_ = (T);                                                         \
        int i_ = rs0 + t_;                                                          \
        i_ = (t_ >= c1) ? (rs1 + t_ - c1) : i_;                                     \
        i_ = (t_ >= c2) ? (rs2 + t_ - c2) : i_;                                     \
        i_ = (t_ >= c3) ? (rs3 + t_ - c3) : i_;                                     \
        i_ = (t_ >= c4) ? (rs4 + t_ - c4) : i_;                                     \
        i_ = (t_ >= c5) ? (rs5 + t_ - c5) : i_;                                     \
        i_ = (t_ >= c6) ? (rs6 + t_ - c6) : i_;                                     \
        i_ = (t_ >= c7) ? (rs7 + t_ - c7) : i_;                                     \
        i_ = (t_ >= c8) ? (rs8 + t_ - c8) : i_;                                     \
        OUTI = (t_ < TT) ? i_ : rs4;   /* rs4 = center's own cell, always valid */  \
    }

    int f0 = BIGJ, f1 = BIGJ, f2 = BIGJ, f3 = BIGJ, f4 = BIGJ, f5 = BIGJ, f6 = BIGJ;
    int cnt = 0;
    int* lst = &lists[wid * 128];
    const unsigned long long ltm = (1ull << lane) - 1ull;

    int ic0;
    CAND_IDX(lane, ic0)
    float4 p_cur = sp[ic0];                           // prologue load (TT >= 1 always)

    for (int t0 = 0; t0 < TT; t0 += 64) {
        int icn;
        CAND_IDX(t0 + 64 + lane, icn)
        const float4 p_nxt = sp[icn];                 // prefetch next chunk

        const bool valid = (t0 + lane) < TT;
        const float4 p = p_cur;
        const int j = __builtin_bit_cast(int, p.w);
        const float psq = sq_exact(p.x, p.y, p.z);    // bit-identical to reference
        float dot = __fadd_rn(__fadd_rn(__fmul_rn(cxf, p.x), __fmul_rn(cyf, p.y)),
                              __fmul_rn(czf, p.z));
        float dd = __fsub_rn(__fadd_rn(csq, psq), __fmul_rn(2.0f, dot));
        const bool ok = valid && (dd <= r2) && (j != n);
        unsigned long long m = __ballot(ok);
        if (m) {
            int pos = cnt + __popcll(m & ltm);
            if (ok && pos < 128) lst[pos] = j;
            cnt += __popcll(m);
            const int oct = ((p.x >= cxf) ? 4 : 0) + ((p.y >= cyf) ? 2 : 0)
                          + ((p.z >= czf) ? 1 : 0);
            const int key = ok ? j : BIGJ;
            f0 = (oct == 0) ? min(f0, key) : f0;
            f1 = (oct == 1) ? min(f1, key) : f1;
            f2 = (oct == 2) ? min(f2, key) : f2;
            f3 = (oct == 3) ? min(f3, key) : f3;
            f4 = (oct == 4) ? min(f4, key) : f4;
            f5 = (oct == 5) ? min(f5, key) : f5;
            f6 = (oct == 6) ? min(f6, key) : f6;
        }
        p_cur = p_nxt;
    }
#undef CAND_IDX

    f0 = wmin(f0); f1 = wmin(f1); f2 = wmin(f2); f3 = wmin(f3);
    f4 = wmin(f4); f5 = wmin(f5); f6 = wmin(f6);

    if (cnt > 31) {
        // rank check against the (<=128) recorded matches; cnt>128 has ~0
        // probability at lambda~30 (same exposure as the sort it replaced)
        const int c2_ = min(cnt, 128);
        const int l0 = (lane < c2_) ? lst[lane] : BIGJ;
        const int l1 = (64 + lane < c2_) ? lst[64 + lane] : BIGJ;
#define RANKCHK(F)                                                                  \
        {                                                                           \
            int r_ = __popcll(__ballot(l0 < F)) + __popcll(__ballot(l1 < F));       \
            F = (r_ <= 30) ? F : BIGJ;                                              \
        }
        RANKCHK(f0) RANKCHK(f1) RANKCHK(f2) RANKCHK(f3)
        RANKCHK(f4) RANKCHK(f5) RANKCHK(f6)
#undef RANKCHK
    }

    int v = n;                                        // lane 0: center index
    if (lane == 1) v = f0;
    if (lane == 2) v = f1;
    if (lane == 3) v = f2;
    if (lane == 4) v = f3;
    if (lane == 5) v = f4;
    if (lane == 6) v = f5;
    if (lane == 7) v = f6;
    if (v > N_PTS) v = N_PTS;                         // BIGJ -> zeros row
    if (lane < 8) idxu[((size_t)((b << 12) | n)) * 8 + lane] = (unsigned short)v;
}

// ---------------- kernel 3: gathered GEMM, 128x128 tile + XCD-local batches --------
// XCD swizzle: XCD k (bid%8) owns 32 contiguous tiles = one half-batch -> per-XCD
// working set = 0.5 MB xbf + 0.5 MB wt, fully L2-resident; gathers become L2 hits
// (R11 probe showed gemm ~16us = HBM-bound on cross-XCD gather misses).
__global__ __launch_bounds__(512) void pconv_gemm(const unsigned short* __restrict__ xbf,
                                                  const unsigned short* __restrict__ wt,
                                                  const unsigned short* __restrict__ idxu,
                                                  const float* __restrict__ bias,
                                                  float* __restrict__ out) {
    __shared__ __attribute__((aligned(16))) unsigned short Plds[2][128 * 64];
    __shared__ __attribute__((aligned(16))) unsigned short Wlds[2][128 * 64];
    __shared__ unsigned short jlds[128 * 8];
    const int tid = threadIdx.x;
    const int tile = ((blockIdx.x & 7) << 5) | (blockIdx.x >> 3);   // XCD-chunked, bijective
    const int tm = tile >> 1, tn = tile & 1;  // 128 M-tiles x 2 N-tiles
    const int g0 = tm * 128;                 // global point-row base
    const int b  = g0 >> 12;
    const int nb = g0 & 4095;
    const int o0 = tn * 128;
    const int wid = tid >> 6, lane = tid & 63;
    const int wo = wid >> 1, wn = wid & 1;   // wave -> 32 o-rows x 64 n-cols

    // hoist all gather indices for this block (1024 u16, coalesced)
    for (int i = tid; i < 1024; i += 512) jlds[i] = idxu[(size_t)g0 * 8 + i];
    __syncthreads();

    f32x4 acc[2][4] = {};

#define STAGE(BUF, IT)                                                              \
    {                                                                               \
        const int k0_ = (IT) << 6;                                                  \
        const int slot_ = (IT) >> 1;                                                \
        const int cb_ = ((IT) & 1) << 6;                                            \
        _Pragma("unroll")                                                           \
        for (int i_ = 0; i_ < 2; ++i_) {                                            \
            const int Lb_ = i_ * 512 + wid * 64;                                    \
            const int row_ = (Lb_ + lane) >> 3;                                     \
            const int slog_ = (lane & 7) ^ (row_ & 7);                              \
            int j_ = jlds[row_ * 8 + slot_];                                        \
            gload_lds16(xbf + ((size_t)b * (N_PTS + 1) + j_) * C_IN + cb_ + slog_ * 8, \
                        &Plds[BUF][Lb_ * 8]);                                       \
            gload_lds16(wt + (size_t)(o0 + row_) * KDIM + k0_ + slog_ * 8,          \
                        &Wlds[BUF][Lb_ * 8]);                                       \
        }                                                                           \
    }

    STAGE(0, 0)
    __syncthreads();                          // vmcnt(0) drain: buf0 ready

    for (int it = 0; it < 16; ++it) {
        const int cur = it & 1;
        if (it + 1 < 16) STAGE(cur ^ 1, it + 1)   // prefetch next K-step
#pragma unroll
        for (int ks = 0; ks < 2; ++ks) {
            bf16x8 wf[2], pf[4];
#pragma unroll
            for (int f = 0; f < 2; ++f) {
                int orow = wo * 32 + f * 16 + (lane & 15);
                int slw = (ks * 4 + (lane >> 4)) ^ (orow & 7);
                wf[f] = *(const bf16x8*)&Wlds[cur][orow * 64 + slw * 8];
            }
#pragma unroll
            for (int q = 0; q < 4; ++q) {
                int nrow = wn * 64 + q * 16 + (lane & 15);
                int slp = (ks * 4 + (lane >> 4)) ^ (nrow & 7);
                pf[q] = *(const bf16x8*)&Plds[cur][nrow * 64 + slp * 8];
            }
#pragma unroll
            for (int f = 0; f < 2; ++f)
#pragma unroll
                for (int q = 0; q < 4; ++q)
                    acc[f][q] = __builtin_amdgcn_mfma_f32_16x16x32_bf16(
                        wf[f], pf[q], acc[f][q], 0, 0, 0);
        }
        __syncthreads();                      // next buf staged + this buf's reads done
    }
#undef STAGE

#pragma unroll
    for (int f = 0; f < 2; ++f) {
        int o = o0 + wo * 32 + f * 16 + (lane >> 4) * 4;
#pragma unroll
        for (int q = 0; q < 4; ++q) {
            int n = nb + wn * 64 + q * 16 + (lane & 15);
#pragma unroll
            for (int r = 0; r < 4; ++r) {
                out[((size_t)b * C_OUT + o + r) * N_PTS + n] = acc[f][q][r] + bias[o + r];
            }
        }
    }
}

extern "C" void kernel_launch(void* const* d_in, const int* in_sizes, int n_in,
                              void* d_out, int out_size, void* d_ws, size_t ws_size,
                              hipStream_t stream) {
    const float* x    = (const float*)d_in[0];
    const float* pcs  = (const float*)d_in[1];
    const float* w    = (const float*)d_in[2];
    const float* bias = (const float*)d_in[3];

    // ws layout (bytes) — total 5,252,112 (proven-safe range):
    char* base = (char*)d_ws;
    float4* sp4 = (float4*)base;                                    //       0 (262,144)
    unsigned short* xbf = (unsigned short*)(base + 262144);         // 4,195,328
    unsigned short* wt  = (unsigned short*)(base + 4457472);        //   524,288
    unsigned short* idxu = (unsigned short*)(base + 4981760);       //   262,144
    int* cellstart = (int*)(base + 5243904);                        //     8,208
    float* out = (float*)d_out;

    hipLaunchKernelGGL(fused_prep, dim3(1288), dim3(256), 0, stream,
                       w, wt, x, xbf, pcs, sp4, cellstart);
    hipLaunchKernelGGL(bq_grid,    dim3(4096), dim3(256), 0, stream,
                       sp4, cellstart, idxu);
    hipLaunchKernelGGL(pconv_gemm, dim3(256),  dim3(512), 0, stream,
                       xbf, wt, idxu, bias, out);
}